// Round 1
// baseline (137.985 us; speedup 1.0000x reference)
//
#include <hip/hip_runtime.h>
#include <math.h>

// Problem constants (from reference: B=1024, N=4096, fp32).
#define BATCH   1024
#define NPTS    4096
#define THREADS 256
#define WAVES   (THREADS / 64)

// Accumulator layout (23 floats):
//  0      : sw        = sum w
//  1..3   : mw[i]     = sum m_i w
//  4..6   : yw[i]     = sum y_i w
//  7..12  : Mw sym    = (00,01,02,11,12,22)
// 13..21  : MY[i][j]  row-major
// 22      : yy        = sum (y.y) w

__global__ __launch_bounds__(THREADS) void locblock_kernel(
    const float* __restrict__ m,   // (B,3,N)
    const float* __restrict__ y,   // (B,3,N)
    const float* __restrict__ w,   // (B,1,N)
    float* __restrict__ out)       // Qn (B*169) | scales (B) | offsets (B)
{
    const int b    = blockIdx.x;
    const int tid  = threadIdx.x;
    const int lane = tid & 63;
    const int wave = tid >> 6;

    const size_t mb = (size_t)b * 3 * NPTS;
    const float4* m0p = (const float4*)(m + mb + 0 * NPTS);
    const float4* m1p = (const float4*)(m + mb + 1 * NPTS);
    const float4* m2p = (const float4*)(m + mb + 2 * NPTS);
    const float4* y0p = (const float4*)(y + mb + 0 * NPTS);
    const float4* y1p = (const float4*)(y + mb + 1 * NPTS);
    const float4* y2p = (const float4*)(y + mb + 2 * NPTS);
    const float4* wp  = (const float4*)(w + (size_t)b * NPTS);

    float acc[23];
#pragma unroll
    for (int i = 0; i < 23; ++i) acc[i] = 0.f;

    auto accum = [&](float wv, float m0v, float m1v, float m2v,
                     float y0v, float y1v, float y2v) {
        float wm0 = wv * m0v, wm1 = wv * m1v, wm2 = wv * m2v;
        acc[0]  += wv;
        acc[1]  += wm0;        acc[2]  += wm1;        acc[3]  += wm2;
        acc[4]  += wv * y0v;   acc[5]  += wv * y1v;   acc[6]  += wv * y2v;
        acc[7]  += wm0 * m0v;  acc[8]  += wm0 * m1v;  acc[9]  += wm0 * m2v;
        acc[10] += wm1 * m1v;  acc[11] += wm1 * m2v;  acc[12] += wm2 * m2v;
        acc[13] += wm0 * y0v;  acc[14] += wm0 * y1v;  acc[15] += wm0 * y2v;
        acc[16] += wm1 * y0v;  acc[17] += wm1 * y1v;  acc[18] += wm1 * y2v;
        acc[19] += wm2 * y0v;  acc[20] += wm2 * y1v;  acc[21] += wm2 * y2v;
        acc[22] += wv * (y0v * y0v + y1v * y1v + y2v * y2v);
    };

    const int NV = NPTS / 4;  // float4 elements per row
#pragma unroll
    for (int v = tid; v < NV; v += THREADS) {
        float4 M0 = m0p[v], M1 = m1p[v], M2 = m2p[v];
        float4 Y0 = y0p[v], Y1 = y1p[v], Y2 = y2p[v];
        float4 W  = wp[v];
        accum(W.x, M0.x, M1.x, M2.x, Y0.x, Y1.x, Y2.x);
        accum(W.y, M0.y, M1.y, M2.y, Y0.y, Y1.y, Y2.y);
        accum(W.z, M0.z, M1.z, M2.z, Y0.z, Y1.z, Y2.z);
        accum(W.w, M0.w, M1.w, M2.w, Y0.w, Y1.w, Y2.w);
    }

    // Wave-level butterfly reduction (64 lanes) for each accumulator.
#pragma unroll
    for (int i = 0; i < 23; ++i) {
        float v = acc[i];
        v += __shfl_xor(v, 32, 64);
        v += __shfl_xor(v, 16, 64);
        v += __shfl_xor(v, 8, 64);
        v += __shfl_xor(v, 4, 64);
        v += __shfl_xor(v, 2, 64);
        v += __shfl_xor(v, 1, 64);
        acc[i] = v;
    }

    __shared__ float partial[WAVES][23];
    __shared__ float sums[23];
    __shared__ float red[WAVES];
    __shared__ float scale_s;

    if (lane == 0) {
#pragma unroll
        for (int i = 0; i < 23; ++i) partial[wave][i] = acc[i];
    }
    __syncthreads();
    if (tid < 23) {
        sums[tid] = partial[0][tid] + partial[1][tid] + partial[2][tid] + partial[3][tid];
    }
    __syncthreads();

    // Assemble one Q entry per thread (169 entries of a 13x13).
    float qv = 0.f;
    if (tid < 169) {
        const int r = tid / 13, c = tid % 13;
        const float sw = sums[0];
        const float* mwv = &sums[1];
        const float* ywv = &sums[4];
        auto Mwf = [&](int i, int j) -> float {
            if (i > j) { int t = i; i = j; j = t; }
            int idx = (i == 0) ? j : ((i == 1) ? (j + 2) : 5);
            return sums[7 + idx];
        };
        auto MYf = [&](int i, int j) -> float { return sums[13 + i * 3 + j]; };

        if (r == 0) {
            if (c == 0)            qv = 0.f;
            else if (c <= 9)       qv = -MYf((c - 1) / 3, (c - 1) % 3);   // Qch
            else                   qv = ywv[c - 10];
        } else if (c == 0) {
            if (r <= 9)            qv = -MYf((r - 1) / 3, (r - 1) % 3);   // Qch
            else                   qv = ywv[r - 10];
        } else if (r <= 9 && c <= 9) {                                    // Qcc
            int a = r - 1, d = c - 1;
            int i = a / 3, k = a % 3, j = d / 3, l = d % 3;
            qv = (k == l) ? Mwf(i, j) : 0.f;
        } else if (r <= 9) {                                              // Qct
            int a = r - 1, i = a / 3, k = a % 3, l = c - 10;
            qv = (k == l) ? -mwv[i] : 0.f;
        } else if (c <= 9) {                                              // Qct^T
            int a = c - 1, i = a / 3, k = a % 3, l = r - 10;
            qv = (k == l) ? -mwv[i] : 0.f;
        } else {                                                          // Qtt
            qv = (r == c) ? sums[0] : 0.f;
        }
        (void)sw;
    }

    // Block-wide sum of squares -> scale.
    float sq = (tid < 169) ? qv * qv : 0.f;
    sq += __shfl_xor(sq, 32, 64);
    sq += __shfl_xor(sq, 16, 64);
    sq += __shfl_xor(sq, 8, 64);
    sq += __shfl_xor(sq, 4, 64);
    sq += __shfl_xor(sq, 2, 64);
    sq += __shfl_xor(sq, 1, 64);
    if (lane == 0) red[wave] = sq;
    __syncthreads();
    if (tid == 0) {
        scale_s = sqrtf(red[0] + red[1] + red[2] + red[3]);
    }
    __syncthreads();

    const float inv_scale = 1.0f / scale_s;
    if (tid < 169) {
        out[(size_t)b * 169 + tid] = qv * inv_scale;
    }
    if (tid == 0) {
        out[(size_t)BATCH * 169 + b]         = scale_s;   // scales
        out[(size_t)BATCH * 169 + BATCH + b] = sums[22];  // offsets (yy)
    }
}

extern "C" void kernel_launch(void* const* d_in, const int* in_sizes, int n_in,
                              void* d_out, int out_size, void* d_ws, size_t ws_size,
                              hipStream_t stream) {
    const float* m = (const float*)d_in[0];  // keypoints_3D_src (B,3,N)
    const float* y = (const float*)d_in[1];  // keypoints_3D_trg (B,3,N)
    const float* w = (const float*)d_in[2];  // weights (B,1,N)
    float* out = (float*)d_out;
    locblock_kernel<<<BATCH, THREADS, 0, stream>>>(m, y, w, out);
}